// Round 7
// baseline (711.793 us; speedup 1.0000x reference)
//
#include <hip/hip_runtime.h>
#include <hip/hip_bf16.h>
#include <cstdint>
#include <cmath>

typedef unsigned short u16;
typedef __attribute__((ext_vector_type(8))) short bf16x8;
typedef __attribute__((ext_vector_type(4))) float f32x4;

__device__ __forceinline__ float bu2f(u16 u) { return __uint_as_float((unsigned)u << 16); }
__device__ __forceinline__ u16 f2bu(float v) {
  union { __hip_bfloat16 h; u16 u; } c; c.h = __float2bfloat16(v); return c.u;
}
__device__ __forceinline__ float ldf(const void* p, size_t i, int f32) {
  return f32 ? ((const float*)p)[i] : bu2f(((const u16*)p)[i]);
}
__device__ __forceinline__ void gll16(const u16* g, u16* lds) {
  __builtin_amdgcn_global_load_lds((const __attribute__((address_space(1))) unsigned*)g,
                                   (__attribute__((address_space(3))) unsigned*)lds, 16, 0, 0);
}

constexpr int Nn = 2048, Bb = 64, Dd = 16, Cc = 66, Hh = 64, BC = 4224;
constexpr int KP = 224;   // padded ki (198 -> 224 = 7*32)

// ---------------------------------------------------------------------------
__global__ void detect_kernel(const void* __restrict__ E, int* __restrict__ flag) {
  if (threadIdx.x == 0) {
    const unsigned* p = (const unsigned*)E;
    int hits = 0;
    for (int i = 0; i < 64; i++) {
      unsigned ex = (p[i] >> 7) & 0xFF;
      hits += (ex >= 100 && ex <= 140) ? 1 : 0;
    }
    *flag = (hits < 32) ? 1 : 0;   // 1 -> inputs are fp32
  }
}

// ---------------------------------------------------------------------------
// Support, wave-per-row: no LDS, no barriers; shfl_xor reductions.
// ---------------------------------------------------------------------------
__global__ __launch_bounds__(256) void support_v2(
    const void* __restrict__ E, const void* __restrict__ mask,
    const int* __restrict__ normalize, const int* __restrict__ flag,
    u16* __restrict__ A) {
  const int f = *flag;
  const int wave = threadIdx.x >> 6, lane = threadIdx.x & 63;
  const int n = blockIdx.x * 4 + wave;

  float en[16];
  if (f) {
    const float* Ef = (const float*)E;
#pragma unroll
    for (int d = 0; d < 16; d++) en[d] = Ef[(size_t)n * 16 + d];
  } else {
    const u16* Eb = (const u16*)E;
#pragma unroll
    for (int d = 0; d < 16; d++) en[d] = bu2f(Eb[(size_t)n * 16 + d]);
  }

  float s[32];
  if (f) {
    const float* Ef = (const float*)E;
#pragma unroll 8
    for (int k = 0; k < 32; k++) {
      const float* er = &Ef[(size_t)(lane + 64 * k) * 16];
      float4 e0 = *(const float4*)&er[0];
      float4 e1 = *(const float4*)&er[4];
      float4 e2 = *(const float4*)&er[8];
      float4 e3 = *(const float4*)&er[12];
      float a = en[0] * e0.x;
      a = fmaf(en[1], e0.y, a);  a = fmaf(en[2], e0.z, a);  a = fmaf(en[3], e0.w, a);
      a = fmaf(en[4], e1.x, a);  a = fmaf(en[5], e1.y, a);  a = fmaf(en[6], e1.z, a);
      a = fmaf(en[7], e1.w, a);  a = fmaf(en[8], e2.x, a);  a = fmaf(en[9], e2.y, a);
      a = fmaf(en[10], e2.z, a); a = fmaf(en[11], e2.w, a); a = fmaf(en[12], e3.x, a);
      a = fmaf(en[13], e3.y, a); a = fmaf(en[14], e3.z, a); a = fmaf(en[15], e3.w, a);
      s[k] = fmaxf(a, 0.f);
    }
  } else {
    const u16* Eb = (const u16*)E;
#pragma unroll 8
    for (int k = 0; k < 32; k++) {
      const u16* er = &Eb[(size_t)(lane + 64 * k) * 16];
      uint4 u0 = *(const uint4*)&er[0];
      uint4 u1 = *(const uint4*)&er[8];
      unsigned w[8] = {u0.x, u0.y, u0.z, u0.w, u1.x, u1.y, u1.z, u1.w};
      float a = 0.f;
#pragma unroll
      for (int i = 0; i < 8; i++) {
        a = fmaf(en[2 * i], bu2f((u16)(w[i] & 0xffff)), a);
        a = fmaf(en[2 * i + 1], bu2f((u16)(w[i] >> 16)), a);
      }
      s[k] = fmaxf(a, 0.f);
    }
  }

  float mx = 0.f;
#pragma unroll
  for (int k = 0; k < 32; k++) mx = fmaxf(mx, s[k]);
#pragma unroll
  for (int off = 1; off < 64; off <<= 1) mx = fmaxf(mx, __shfl_xor(mx, off, 64));
  float sum = 0.f;
#pragma unroll
  for (int k = 0; k < 32; k++) { s[k] = expf(s[k] - mx); sum += s[k]; }
#pragma unroll
  for (int off = 1; off < 64; off <<= 1) sum += __shfl_xor(sum, off, 64);
  float inv = 1.f / sum;

  if (f) {
    const float* Mf = (const float*)mask;
#pragma unroll 8
    for (int k = 0; k < 32; k++)
      s[k] = s[k] * inv * Mf[(size_t)n * Nn + lane + 64 * k];
  } else {
    const u16* Mb = (const u16*)mask;
#pragma unroll 8
    for (int k = 0; k < 32; k++)
      s[k] = s[k] * inv * bu2f(Mb[(size_t)n * Nn + lane + 64 * k]);
  }

  if (*normalize != 0) {
    float mx2 = -1e30f;
#pragma unroll
    for (int k = 0; k < 32; k++) mx2 = fmaxf(mx2, s[k]);
#pragma unroll
    for (int off = 1; off < 64; off <<= 1) mx2 = fmaxf(mx2, __shfl_xor(mx2, off, 64));
    float sm2 = 0.f;
#pragma unroll
    for (int k = 0; k < 32; k++) { s[k] = expf(s[k] - mx2); sm2 += s[k]; }
#pragma unroll
    for (int off = 1; off < 64; off <<= 1) sm2 += __shfl_xor(sm2, off, 64);
    float inv2 = 1.f / sm2;
#pragma unroll
    for (int k = 0; k < 32; k++) s[k] *= inv2;
  }

#pragma unroll
  for (int k = 0; k < 32; k++)
    A[(size_t)n * Nn + lane + 64 * k] = f2bu(s[k]);
}

// ---------------------------------------------------------------------------
__global__ __launch_bounds__(256) void build_xt_kernel(
    const void* __restrict__ x, const void* __restrict__ state,
    const int* __restrict__ flag, u16* __restrict__ Xt) {
  __shared__ float sx[66][65];
  int f = *flag;
  int m0 = blockIdx.x * 64, b = blockIdx.y;
  int t = threadIdx.x;
  {
    int cl = t & 63, mg = t >> 6;
    for (int cb = 0; cb < 2; cb++) {
      int c = cb * 64 + cl;
      if (c < 66)
        for (int m = mg; m < 64; m += 4)
          sx[c][m] = (c < 2) ? ldf(x, ((size_t)b * Nn + m0 + m) * 2 + c, f)
                             : ldf(state, ((size_t)b * Nn + m0 + m) * Hh + (c - 2), f);
    }
  }
  __syncthreads();
  for (int cb = 0; cb < 2; cb++) {
    int ch = t >> 2;
    int c = cb * 64 + ch;
    if (c < 66 && (cb == 0 || ch < 2)) {
      int mq = t & 3;
      __align__(16) u16 tmp[16];
#pragma unroll
      for (int i = 0; i < 16; i++) tmp[i] = f2bu(sx[c][mq * 16 + i]);
      *(uint4*)&Xt[(size_t)(b * 66 + c) * 2048 + m0 + mq * 16] = *(uint4*)&tmp[0];
      *(uint4*)&Xt[(size_t)(b * 66 + c) * 2048 + m0 + mq * 16 + 8] = *(uint4*)&tmp[8];
    }
  }
}

// ---------------------------------------------------------------------------
// MFMA GEMM with LDS-staged vectorized epilogue for C (node-major) and
// optional Ct (transposed).
// ---------------------------------------------------------------------------
__global__ __launch_bounds__(256) void gemm_bt(
    const u16* __restrict__ A, const u16* __restrict__ Bt,
    u16* __restrict__ C, u16* __restrict__ Ct) {
  __shared__ __align__(16) u16 As[128 * 32];
  __shared__ __align__(16) u16 Bs[128 * 32];
  __shared__ __align__(16) u16 ep[64 * 136];
  const int t = threadIdx.x;
  const int wave = t >> 6, lane = t & 63;
  const int bm = blockIdx.y * 128, bj = blockIdx.x * 128;
  const int wm = (wave >> 1) * 64, wj = (wave & 1) * 64;
  const int lr = lane >> 2;
  const int gc = (lane & 3) ^ (lr & 3);
  const int ln = lane & 15, q = lane >> 4;
  const int sw = ((q ^ (ln & 3)) << 3);

  f32x4 acc[4][4];
#pragma unroll
  for (int i = 0; i < 4; i++)
#pragma unroll
    for (int j = 0; j < 4; j++) acc[i][j] = (f32x4){0.f, 0.f, 0.f, 0.f};

  for (int k0 = 0; k0 < 2048; k0 += 32) {
#pragma unroll
    for (int p = 0; p < 2; p++) {
      int rb = wave * 32 + p * 16;
      gll16(&A[(size_t)(bm + rb + lr) * 2048 + k0 + gc * 8], &As[rb * 32]);
      gll16(&Bt[(size_t)(bj + rb + lr) * 2048 + k0 + gc * 8], &Bs[rb * 32]);
    }
    __syncthreads();
    bf16x8 af[4], bfr[4];
#pragma unroll
    for (int i = 0; i < 4; i++) af[i] = *(const bf16x8*)&As[(wm + i * 16 + ln) * 32 + sw];
#pragma unroll
    for (int j = 0; j < 4; j++) bfr[j] = *(const bf16x8*)&Bs[(wj + j * 16 + ln) * 32 + sw];
#pragma unroll
    for (int i = 0; i < 4; i++)
#pragma unroll
      for (int j = 0; j < 4; j++)
        acc[i][j] = __builtin_amdgcn_mfma_f32_16x16x32_bf16(af[i], bfr[j], acc[i][j], 0, 0, 0);
    __syncthreads();
  }

  // epilogue: C node-major, two 64-row halves through LDS
  for (int h = 0; h < 2; h++) {
    if ((wave >> 1) == h) {
#pragma unroll
      for (int i = 0; i < 4; i++)
#pragma unroll
        for (int j = 0; j < 4; j++)
#pragma unroll
          for (int r = 0; r < 4; r++)
            ep[(i * 16 + q * 4 + r) * 136 + wj + j * 16 + ln] = f2bu(acc[i][j][r]);
    }
    __syncthreads();
    {
      int rl = t >> 2, sg = t & 3;
      size_t base = (size_t)(bm + h * 64 + rl) * 4224 + bj + sg * 32;
#pragma unroll
      for (int k = 0; k < 4; k++)
        *(uint4*)&C[base + k * 8] = *(const uint4*)&ep[rl * 136 + sg * 32 + k * 8];
    }
    __syncthreads();
  }
  // epilogue: Ct transposed, two 64-col halves
  if (Ct) {
    for (int jh = 0; jh < 2; jh++) {
      if ((wave & 1) == jh) {
#pragma unroll
        for (int i = 0; i < 4; i++)
#pragma unroll
          for (int j = 0; j < 4; j++)
#pragma unroll
            for (int r = 0; r < 4; r++)
              ep[(j * 16 + ln) * 136 + wm + i * 16 + q * 4 + r] = f2bu(acc[i][j][r]);
      }
      __syncthreads();
      {
        int jl = t >> 2, sg = t & 3;
        size_t base = (size_t)(bj + jh * 64 + jl) * 2048 + bm + sg * 32;
#pragma unroll
        for (int k = 0; k < 4; k++)
          *(uint4*)&Ct[base + k * 8] = *(const uint4*)&ep[jl * 136 + sg * 32 + k * 8];
      }
      __syncthreads();
    }
  }
}

// ---------------------------------------------------------------------------
__global__ __launch_bounds__(256) void transpose_kernel(
    const u16* __restrict__ S, u16* __restrict__ D) {
  __shared__ u16 sm[64][70];
  int j0 = blockIdx.x * 64, m0 = blockIdx.y * 64;
  int t = threadIdx.x;
  {
    int c = t & 63, r0 = t >> 6;
    for (int r = r0; r < 64; r += 4)
      sm[r][c] = S[(size_t)(m0 + r) * 4224 + j0 + c];
  }
  __syncthreads();
  {
    int jl = t >> 2, mq = t & 3;
    __align__(16) u16 tmp[16];
#pragma unroll
    for (int i = 0; i < 16; i++) tmp[i] = sm[mq * 16 + i][jl];
    *(uint4*)&D[(size_t)(j0 + jl) * 2048 + m0 + mq * 16] = *(uint4*)&tmp[0];
    *(uint4*)&D[(size_t)(j0 + jl) * 2048 + m0 + mq * 16 + 8] = *(uint4*)&tmp[8];
  }
}

// ---------------------------------------------------------------------------
// Fold: Wnt[n_rel][o][KP] (bf16) = sum_d E[n,d] * W[d][ki][o]
// ---------------------------------------------------------------------------
__global__ __launch_bounds__(256) void fold_kernel(
    const void* __restrict__ E, const void* __restrict__ W,
    u16* __restrict__ Wnt, const int* __restrict__ flag, int n0, int O) {
  __shared__ float Es[64][16];
  const int f = *flag;
  const int t = threadIdx.x;
  const int nb = n0 + blockIdx.x * 64;
  const int ki0 = blockIdx.y * 8;
  for (int j = t; j < 1024; j += 256)
    Es[j >> 4][j & 15] = ldf(E, (size_t)(nb + (j >> 4)) * 16 + (j & 15), f);

  const int o = t & (O - 1);
  const int tpn = 256 / O;
  const int nh = t / O;
  const int NPT = 64 / tpn;

  float wv[128];
  if (f) {
    const float* Wf = (const float*)W;
#pragma unroll
    for (int d = 0; d < 16; d++)
#pragma unroll
      for (int i = 0; i < 8; i++) {
        int ki = ki0 + i;
        wv[d * 8 + i] = (ki < 198) ? Wf[((size_t)d * 198 + ki) * O + o] : 0.f;
      }
  } else {
    const u16* Wb = (const u16*)W;
#pragma unroll
    for (int d = 0; d < 16; d++)
#pragma unroll
      for (int i = 0; i < 8; i++) {
        int ki = ki0 + i;
        wv[d * 8 + i] = (ki < 198) ? bu2f(Wb[((size_t)d * 198 + ki) * O + o]) : 0.f;
      }
  }
  __syncthreads();

  for (int r = 0; r < NPT; r++) {
    int nl = nh * NPT + r;
    float en[16];
#pragma unroll
    for (int d = 0; d < 16; d++) en[d] = Es[nl][d];
    float a8[8];
#pragma unroll
    for (int i = 0; i < 8; i++) a8[i] = 0.f;
#pragma unroll
    for (int d = 0; d < 16; d++)
#pragma unroll
      for (int i = 0; i < 8; i++) a8[i] = fmaf(en[d], wv[d * 8 + i], a8[i]);
    unsigned pw[4];
#pragma unroll
    for (int i = 0; i < 4; i++)
      pw[i] = (unsigned)f2bu(a8[2 * i]) | ((unsigned)f2bu(a8[2 * i + 1]) << 16);
    *(uint4*)&Wnt[((size_t)(blockIdx.x * 64 + nl) * O + o) * KP + ki0] =
        make_uint4(pw[0], pw[1], pw[2], pw[3]);
  }
}

// ---------------------------------------------------------------------------
// MFMA per-node einsum, gate (O=128)
// ---------------------------------------------------------------------------
__global__ __launch_bounds__(256) void avw_gate(
    const u16* __restrict__ Y1, const u16* __restrict__ Y2,
    const void* __restrict__ x, const void* __restrict__ state,
    const void* __restrict__ E, const u16* __restrict__ Wnt,
    const void* __restrict__ bp, const int* __restrict__ flag,
    void* Rout, u16* __restrict__ XC, int n0) {
  __shared__ unsigned xg32[64][116];
  __shared__ float en_s[16];
  const int f = *flag;
  const int bx = blockIdx.x;
  const int n = n0 + bx;
  const int t = threadIdx.x;
  if (t < 16) en_s[t] = ldf(E, (size_t)n * 16 + t, f);

  const unsigned* Y1u = (const unsigned*)(Y1 + (size_t)n * BC);
  const unsigned* Y2u = (const unsigned*)(Y2 + (size_t)n * BC);
  for (int j = t; j < 64 * 33; j += 256) {
    int b = j / 33, cp = j - b * 33, c = cp * 2;
    float x0, x1;
    if (cp == 0) {
      x0 = ldf(x, ((size_t)b * Nn + n) * 2 + 0, f);
      x1 = ldf(x, ((size_t)b * Nn + n) * 2 + 1, f);
    } else {
      x0 = ldf(state, ((size_t)b * Nn + n) * Hh + (c - 2), f);
      x1 = ldf(state, ((size_t)b * Nn + n) * Hh + (c - 1), f);
    }
    unsigned y1 = Y1u[b * 33 + cp];
    unsigned y2 = Y2u[b * 33 + cp];
    float t20 = 2.f * bu2f((u16)(y2 & 0xffff)) - x0;
    float t21 = 2.f * bu2f((u16)(y2 >> 16)) - x1;
    xg32[b][cp]      = (unsigned)f2bu(x0) | ((unsigned)f2bu(x1) << 16);
    xg32[b][33 + cp] = y1;
    xg32[b][66 + cp] = (unsigned)f2bu(t20) | ((unsigned)f2bu(t21) << 16);
  }
  for (int j = t; j < 64 * 17; j += 256) xg32[j / 17][99 + (j - (j / 17) * 17)] = 0u;
  __syncthreads();

  const int wave = t >> 6, lane = t & 63;
  const int ln = lane & 15, q = lane >> 4;
  f32x4 acc[4][2];
#pragma unroll
  for (int i = 0; i < 4; i++) { acc[i][0] = (f32x4){0,0,0,0}; acc[i][1] = (f32x4){0,0,0,0}; }

  const u16* Wrow = Wnt + (size_t)bx * 128 * KP;
  const u16* xg16 = (const u16*)&xg32[0][0];
  for (int k0 = 0; k0 < KP; k0 += 32) {
    bf16x8 bfr[2];
#pragma unroll
    for (int oi = 0; oi < 2; oi++) {
      int o = (wave * 2 + oi) * 16 + ln;
      bfr[oi] = *(const bf16x8*)&Wrow[(size_t)o * KP + k0 + q * 8];
    }
#pragma unroll
    for (int mt = 0; mt < 4; mt++) {
      bf16x8 af = *(const bf16x8*)&xg16[(mt * 16 + ln) * 232 + k0 + q * 8];
      acc[mt][0] = __builtin_amdgcn_mfma_f32_16x16x32_bf16(af, bfr[0], acc[mt][0], 0, 0, 0);
      acc[mt][1] = __builtin_amdgcn_mfma_f32_16x16x32_bf16(af, bfr[1], acc[mt][1], 0, 0, 0);
    }
  }

  float bias[2];
#pragma unroll
  for (int oi = 0; oi < 2; oi++) {
    int o = (wave * 2 + oi) * 16 + ln;
    float s = 0.f;
#pragma unroll
    for (int d = 0; d < 16; d++) s += en_s[d] * ldf(bp, (size_t)d * 128 + o, f);
    bias[oi] = s;
  }
#pragma unroll
  for (int mt = 0; mt < 4; mt++)
#pragma unroll
    for (int oi = 0; oi < 2; oi++) {
      int o = (wave * 2 + oi) * 16 + ln;
#pragma unroll
      for (int r = 0; r < 4; r++) {
        int b = mt * 16 + q * 4 + r;
        float v = 1.f / (1.f + expf(-(acc[mt][oi][r] + bias[oi])));
        if (o < 64) {
          float s = ldf(state, ((size_t)b * Nn + n) * Hh + o, f);
          XC[(size_t)n * BC + b * 66 + 2 + o] = f2bu(v * s);
        } else {
          size_t idx = ((size_t)b * Nn + n) * Hh + (o - 64);
          if (f) ((float*)Rout)[idx] = v; else ((u16*)Rout)[idx] = f2bu(v);
        }
      }
    }
  if (t < 128) {
    int b = t >> 1, c = t & 1;
    XC[(size_t)n * BC + b * 66 + c] = f2bu(ldf(x, ((size_t)b * Nn + n) * 2 + c, f));
  }
}

// ---------------------------------------------------------------------------
// MFMA per-node einsum, update (O=64)
// ---------------------------------------------------------------------------
__global__ __launch_bounds__(256) void avw_update(
    const u16* __restrict__ XCn, const u16* __restrict__ Y1, const u16* __restrict__ Y2,
    const void* __restrict__ E, const u16* __restrict__ Wnt,
    const void* __restrict__ bp, const void* __restrict__ state,
    const int* __restrict__ flag, void* out, int n0) {
  __shared__ unsigned xg32[64][116];
  __shared__ float en_s[16];
  const int f = *flag;
  const int bx = blockIdx.x;
  const int n = n0 + bx;
  const int t = threadIdx.x;
  if (t < 16) en_s[t] = ldf(E, (size_t)n * 16 + t, f);

  const unsigned* XCu = (const unsigned*)(XCn + (size_t)n * BC);
  const unsigned* Y1u = (const unsigned*)(Y1 + (size_t)n * BC);
  const unsigned* Y2u = (const unsigned*)(Y2 + (size_t)n * BC);
  for (int j = t; j < 64 * 33; j += 256) {
    int b = j / 33, cp = j - b * 33;
    unsigned x01 = XCu[b * 33 + cp];
    unsigned y1 = Y1u[b * 33 + cp];
    unsigned y2 = Y2u[b * 33 + cp];
    float x0 = bu2f((u16)(x01 & 0xffff)), x1 = bu2f((u16)(x01 >> 16));
    float t20 = 2.f * bu2f((u16)(y2 & 0xffff)) - x0;
    float t21 = 2.f * bu2f((u16)(y2 >> 16)) - x1;
    xg32[b][cp]      = x01;
    xg32[b][33 + cp] = y1;
    xg32[b][66 + cp] = (unsigned)f2bu(t20) | ((unsigned)f2bu(t21) << 16);
  }
  for (int j = t; j < 64 * 17; j += 256) xg32[j / 17][99 + (j - (j / 17) * 17)] = 0u;
  __syncthreads();

  const int wave = t >> 6, lane = t & 63;
  const int ln = lane & 15, q = lane >> 4;
  f32x4 acc[4];
#pragma unroll
  for (int i = 0; i < 4; i++) acc[i] = (f32x4){0, 0, 0, 0};

  const u16* Wrow = Wnt + (size_t)bx * 64 * KP;
  const u16* xg16 = (const u16*)&xg32[0][0];
  const int o = wave * 16 + ln;
  for (int k0 = 0; k0 < KP; k0 += 32) {
    bf16x8 bfr = *(const bf16x8*)&Wrow[(size_t)o * KP + k0 + q * 8];
#pragma unroll
    for (int mt = 0; mt < 4; mt++) {
      bf16x8 af = *(const bf16x8*)&xg16[(mt * 16 + ln) * 232 + k0 + q * 8];
      acc[mt] = __builtin_amdgcn_mfma_f32_16x16x32_bf16(af, bfr, acc[mt], 0, 0, 0);
    }
  }

  float bias = 0.f;
#pragma unroll
  for (int d = 0; d < 16; d++) bias += en_s[d] * ldf(bp, (size_t)d * 64 + o, f);
#pragma unroll
  for (int mt = 0; mt < 4; mt++)
#pragma unroll
    for (int r = 0; r < 4; r++) {
      int b = mt * 16 + q * 4 + r;
      size_t idx = ((size_t)b * Nn + n) * Hh + o;
      float hc = tanhf(acc[mt][r] + bias);
      float rr = f ? ((const float*)out)[idx] : bu2f(((const u16*)out)[idx]);
      float s = ldf(state, idx, f);
      float v = rr * s + (1.f - rr) * hc;
      if (f) ((float*)out)[idx] = v; else ((u16*)out)[idx] = f2bu(v);
    }
}

// ---------------------------------------------------------------------------
// Fallback gate/update for tiny workspaces
// ---------------------------------------------------------------------------
__global__ __launch_bounds__(256) void gate_kernel_fb(
    const u16* __restrict__ Y1, const u16* __restrict__ Y2,
    const void* __restrict__ x, const void* __restrict__ state,
    const void* __restrict__ E, const void* __restrict__ W, const void* __restrict__ bp,
    const int* __restrict__ flag, void* Rout, u16* __restrict__ XC) {
  __shared__ float xg[64][208];
  __shared__ float wnc[128][20];
  __shared__ float en_s[16];
  const int f = *flag;
  const int n = blockIdx.x, t = threadIdx.x;
  if (t < 16) en_s[t] = ldf(E, (size_t)n * 16 + t, f);
  for (int j = t; j < 64 * 66; j += 256) {
    int b = j / 66, c = j - b * 66;
    float v0 = (c < 2) ? ldf(x, ((size_t)b * Nn + n) * 2 + c, f)
                       : ldf(state, ((size_t)b * Nn + n) * Hh + (c - 2), f);
    xg[b][c] = v0;
    xg[b][66 + c] = bu2f(Y1[(size_t)n * BC + j]);
    xg[b][132 + c] = 2.f * bu2f(Y2[(size_t)n * BC + j]) - v0;
  }
  for (int j = t; j < 64 * 10; j += 256) xg[j / 10][198 + (j % 10)] = 0.f;
  const int o8 = t & 15, kl = t >> 4;
  const int o = t & 127, bg = t >> 7;
  float acc[32];
#pragma unroll
  for (int i = 0; i < 32; i++) acc[i] = 0.f;
  for (int c0 = 0; c0 < 208; c0 += 16) {
    __syncthreads();
    {
      int ki = c0 + kl;
      float a8[8];
#pragma unroll
      for (int j = 0; j < 8; j++) a8[j] = 0.f;
      if (ki < 198) {
#pragma unroll
        for (int d = 0; d < 16; d++) {
          float e = en_s[d];
#pragma unroll
          for (int j = 0; j < 8; j++)
            a8[j] = fmaf(e, ldf(W, (size_t)(d * 198 + ki) * 128 + o8 * 8 + j, f), a8[j]);
        }
      }
#pragma unroll
      for (int j = 0; j < 8; j++) wnc[o8 * 8 + j][kl] = a8[j];
    }
    __syncthreads();
#pragma unroll 1
    for (int kq = 0; kq < 4; kq++) {
      float4 wv = *(const float4*)&wnc[o][kq * 4];
#pragma unroll
      for (int bi = 0; bi < 32; bi++) {
        float4 xv = *(const float4*)&xg[bg * 32 + bi][c0 + kq * 4];
        acc[bi] = fmaf(wv.x, xv.x, acc[bi]); acc[bi] = fmaf(wv.y, xv.y, acc[bi]);
        acc[bi] = fmaf(wv.z, xv.z, acc[bi]); acc[bi] = fmaf(wv.w, xv.w, acc[bi]);
      }
    }
  }
  float bias = 0.f;
#pragma unroll
  for (int d = 0; d < 16; d++) bias += en_s[d] * ldf(bp, (size_t)d * 128 + o, f);
#pragma unroll
  for (int bi = 0; bi < 32; bi++) {
    int b = bg * 32 + bi;
    float v = 1.f / (1.f + expf(-(acc[bi] + bias)));
    if (o < 64) {
      float s = ldf(state, ((size_t)b * Nn + n) * Hh + o, f);
      XC[(size_t)n * BC + b * 66 + 2 + o] = f2bu(v * s);
    } else {
      size_t idx = ((size_t)b * Nn + n) * Hh + (o - 64);
      if (f) ((float*)Rout)[idx] = v; else ((u16*)Rout)[idx] = f2bu(v);
    }
  }
  if (t < 128) {
    int b = t >> 1, c = t & 1;
    XC[(size_t)n * BC + b * 66 + c] = f2bu(ldf(x, ((size_t)b * Nn + n) * 2 + c, f));
  }
}

__global__ __launch_bounds__(256) void update_kernel_fb(
    const u16* __restrict__ XCn, const u16* __restrict__ Y1, const u16* __restrict__ Y2,
    const void* __restrict__ E, const void* __restrict__ W, const void* __restrict__ bp,
    const void* __restrict__ state, const int* __restrict__ flag, void* out) {
  __shared__ float xg[64][208];
  __shared__ float wnc[64][20];
  __shared__ float en_s[16];
  const int f = *flag;
  const int n = blockIdx.x, t = threadIdx.x;
  if (t < 16) en_s[t] = ldf(E, (size_t)n * 16 + t, f);
  for (int j = t; j < 64 * 66; j += 256) {
    int b = j / 66, c = j - b * 66;
    float v0 = bu2f(XCn[(size_t)n * BC + j]);
    xg[b][c] = v0;
    xg[b][66 + c] = bu2f(Y1[(size_t)n * BC + j]);
    xg[b][132 + c] = 2.f * bu2f(Y2[(size_t)n * BC + j]) - v0;
  }
  for (int j = t; j < 64 * 10; j += 256) xg[j / 10][198 + (j % 10)] = 0.f;
  const int o4 = t & 15, kl = t >> 4;
  const int o = t & 63, bg = t >> 6;
  float acc[16];
#pragma unroll
  for (int i = 0; i < 16; i++) acc[i] = 0.f;
  for (int c0 = 0; c0 < 208; c0 += 16) {
    __syncthreads();
    {
      int ki = c0 + kl;
      float a4[4];
#pragma unroll
      for (int j = 0; j < 4; j++) a4[j] = 0.f;
      if (ki < 198) {
#pragma unroll
        for (int d = 0; d < 16; d++) {
          float e = en_s[d];
#pragma unroll
          for (int j = 0; j < 4; j++)
            a4[j] = fmaf(e, ldf(W, (size_t)(d * 198 + ki) * 64 + o4 * 4 + j, f), a4[j]);
        }
      }
#pragma unroll
      for (int j = 0; j < 4; j++) wnc[o4 * 4 + j][kl] = a4[j];
    }
    __syncthreads();
#pragma unroll 1
    for (int kq = 0; kq < 4; kq++) {
      float4 wv = *(const float4*)&wnc[o][kq * 4];
#pragma unroll
      for (int bi = 0; bi < 16; bi++) {
        float4 xv = *(const float4*)&xg[bg * 16 + bi][c0 + kq * 4];
        acc[bi] = fmaf(wv.x, xv.x, acc[bi]); acc[bi] = fmaf(wv.y, xv.y, acc[bi]);
        acc[bi] = fmaf(wv.z, xv.z, acc[bi]); acc[bi] = fmaf(wv.w, xv.w, acc[bi]);
      }
    }
  }
  float bias = 0.f;
#pragma unroll
  for (int d = 0; d < 16; d++) bias += en_s[d] * ldf(bp, (size_t)d * 64 + o, f);
#pragma unroll
  for (int bi = 0; bi < 16; bi++) {
    int b = bg * 16 + bi;
    size_t idx = ((size_t)b * Nn + n) * Hh + o;
    float hc = tanhf(acc[bi] + bias);
    float r = f ? ((const float*)out)[idx] : bu2f(((const u16*)out)[idx]);
    float s = ldf(state, idx, f);
    float v = r * s + (1.f - r) * hc;
    if (f) ((float*)out)[idx] = v; else ((u16*)out)[idx] = f2bu(v);
  }
}

// ---------------------------------------------------------------------------
extern "C" void kernel_launch(void* const* d_in, const int* in_sizes, int n_in,
                              void* d_out, int out_size, void* d_ws, size_t ws_size,
                              hipStream_t stream) {
  const void* x     = d_in[0];
  const void* state = d_in[1];
  const void* E     = d_in[2];
  const void* mask  = d_in[3];
  const void* gW    = d_in[4];
  const void* gb    = d_in[5];
  const void* uW    = d_in[6];
  const void* ub    = d_in[7];
  const int* normalize = (const int*)d_in[8];

  char* w = (char*)d_ws;
  int* flag = (int*)w;
  u16* A   = (u16*)(w + 64);
  u16* Xt  = A + (size_t)Nn * Nn;        // later: XC (candidate, node-major)
  u16* Y1t = Xt + (size_t)Nn * BC;
  u16* Y1  = Y1t + (size_t)Nn * BC;
  u16* Q   = Y1 + (size_t)Nn * BC;       // Y2 / XCt / Y2'
  size_t base = 64 + (size_t)Nn * Nn * 2 + 4 * (size_t)Nn * BC * 2;
  size_t wntOff = (base + 255) & ~(size_t)255;

  // cs=512: Wnt chunk (29.4 MB gate / 14.7 MB update) stays L3-resident
  // between fold(c) and avw(c); 512 blocks ≈ resident concurrency anyway.
  int cs = 0;
  for (int c = 512; c >= 64; c >>= 1)
    if (wntOff + (size_t)c * 128 * KP * 2 <= ws_size) { cs = c; break; }
  u16* Wnt = (u16*)(w + wntOff);

  detect_kernel<<<1, 64, 0, stream>>>(E, flag);
  support_v2<<<Nn / 4, 256, 0, stream>>>(E, mask, normalize, flag, A);
  build_xt_kernel<<<dim3(32, 64), 256, 0, stream>>>(x, state, flag, Xt);

  dim3 g(33, 16);
  gemm_bt<<<g, 256, 0, stream>>>(A, Xt, Y1, Y1t);        // Y1 = A@X   (+Y1t)
  gemm_bt<<<g, 256, 0, stream>>>(A, Y1t, Q, nullptr);    // Y2 = A@Y1

  if (cs) {
    for (int c0 = 0; c0 < Nn; c0 += cs) {
      fold_kernel<<<dim3(cs / 64, 28), 256, 0, stream>>>(E, gW, Wnt, flag, c0, 128);
      avw_gate<<<cs, 256, 0, stream>>>(Y1, Q, x, state, E, Wnt, gb, flag, d_out, Xt, c0);
    }
  } else {
    gate_kernel_fb<<<Nn, 256, 0, stream>>>(Y1, Q, x, state, E, gW, gb, flag, d_out, Xt);
  }

  transpose_kernel<<<dim3(66, 32), 256, 0, stream>>>(Xt, Q);   // XCt
  gemm_bt<<<g, 256, 0, stream>>>(A, Q, Y1, Y1t);         // Y1 = A@XC  (+Y1t)
  gemm_bt<<<g, 256, 0, stream>>>(A, Y1t, Q, nullptr);    // Y2' = A@Y1

  if (cs) {
    for (int c0 = 0; c0 < Nn; c0 += cs) {
      fold_kernel<<<dim3(cs / 64, 28), 256, 0, stream>>>(E, uW, Wnt, flag, c0, 64);
      avw_update<<<cs, 256, 0, stream>>>(Xt, Y1, Q, E, Wnt, ub, state, flag, d_out, c0);
    }
  } else {
    update_kernel_fb<<<Nn, 256, 0, stream>>>(Xt, Y1, Q, E, uW, ub, state, flag, d_out);
  }
}